// Round 9
// baseline (356.757 us; speedup 1.0000x reference)
//
#include <hip/hip_runtime.h>

#define N_NODES 100000
#define N_EDGES 1200000
#define R_BUCKETS 256
#define RSZ 400              // 256 * 400 = 102400 >= N
#define CAP 8192             // per-bucket segment capacity (mean 4688, sigma 68 -> safe)
#define CH 4096
#define NC 293               // ceil(1200000 / 4096)

typedef _Float16 h8 __attribute__((ext_vector_type(8)));
typedef float f32x16 __attribute__((ext_vector_type(16)));

// ================= CSR build: segmented buckets, no global scan =================
// S1: per-chunk LDS histogram -> one global atomicAdd per (chunk,bucket) -> LDS-ticket scatter
__global__ __launch_bounds__(256) void bkt_scatter(const int* __restrict__ src,
                                                   const int* __restrict__ dst,
                                                   int* __restrict__ bucket_alloc,
                                                   int2* __restrict__ ebuf, int E) {
    __shared__ int h[R_BUCKETS];
    __shared__ int off[R_BUCKETS];
    h[threadIdx.x] = 0;
    __syncthreads();
    int e0 = blockIdx.x * CH;
    int e1 = min(e0 + CH, E);
    for (int e = e0 + (int)threadIdx.x; e < e1; e += 256)
        atomicAdd(&h[dst[e] / RSZ], 1);
    __syncthreads();
    int b = threadIdx.x;
    int hc = h[b];
    off[b] = b * CAP + (hc > 0 ? atomicAdd(&bucket_alloc[b], hc) : 0);
    __syncthreads();
    for (int e = e0 + (int)threadIdx.x; e < e1; e += 256) {
        int d = dst[e];
        int p = atomicAdd(&off[d / RSZ], 1);
        ebuf[p] = make_int2(src[e], d);
    }
}

// S2: per-bucket (256 blocks): LDS hist -> dinv, LDS scan -> row2, ticket pass -> csr
__global__ __launch_bounds__(256) void bkt_build(const int2* __restrict__ ebuf,
                                                 const int* __restrict__ bcnt,
                                                 int2* __restrict__ row2,
                                                 float* __restrict__ dinv,
                                                 int* __restrict__ csr, int N) {
    __shared__ int hist[RSZ];
    __shared__ int pref[RSZ];
    __shared__ int part[256];
    int r = blockIdx.x;
    int nbase = r * RSZ;
    int ebase = r * CAP;
    int ecnt = bcnt[r];
    for (int i = threadIdx.x; i < RSZ; i += 256) hist[i] = 0;
    __syncthreads();
    for (int e = (int)threadIdx.x; e < ecnt; e += 256)
        atomicAdd(&hist[ebuf[ebase + e].y - nbase], 1);
    __syncthreads();
    for (int i = threadIdx.x; i < RSZ; i += 256) {
        int gi = nbase + i;
        if (gi < N) dinv[gi] = rsqrtf((float)hist[i] + 1.0f);  // +1 self loop
    }
    // exclusive scan of hist (2 bins/thread; RSZ=400 even)
    int s0 = threadIdx.x * 2;
    int sum = (s0 < RSZ) ? hist[s0] + hist[s0 + 1] : 0;
    part[threadIdx.x] = sum;
    __syncthreads();
    for (int off = 1; off < 256; off <<= 1) {
        int v = (threadIdx.x >= off) ? part[threadIdx.x - off] : 0;
        __syncthreads();
        part[threadIdx.x] += v;
        __syncthreads();
    }
    if (s0 < RSZ) {
        int run = part[threadIdx.x] - sum;
        pref[s0] = run;
        pref[s0 + 1] = run + hist[s0];
    }
    __syncthreads();
    for (int i = threadIdx.x; i < RSZ; i += 256) {
        int gi = nbase + i;
        if (gi < N) row2[gi] = make_int2(ebase + pref[i], ebase + pref[i] + hist[i]);
    }
    __syncthreads();
    for (int e = (int)threadIdx.x; e < ecnt; e += 256) {
        int2 sd = ebuf[ebase + e];
        int t = atomicAdd(&pref[sd.y - nbase], 1);
        csr[ebase + t] = sd.x;
    }
}

// ================= w2l = W2 @ Wl =================
__global__ void w2l_kernel(const float* __restrict__ W2, const float* __restrict__ Wl,
                           float* __restrict__ w2l) {
    int f = threadIdx.x;  // 64 threads
    float s = 0.0f;
    for (int o = 0; o < 64; o++) s += W2[f * 64 + o] * Wl[o];
    w2l[f] = s;
}

// ===== W1 -> split-fp16 B-fragments for mfma_f32_32x32x16_f16 =====
__global__ void w1split_kernel(const float* __restrict__ W1, _Float16* __restrict__ whi,
                               _Float16* __restrict__ wlo) {
    int idx = blockIdx.x * 256 + threadIdx.x;  // 2*8*64*8 = 8192
    if (idx >= 8192) return;
    int j = idx & 7;
    int lane = (idx >> 3) & 63;
    int kk = (idx >> 9) & 7;
    int nt = idx >> 12;
    int k = kk * 16 + (lane >> 5) * 8 + j;
    int n = nt * 32 + (lane & 31);
    float v = W1[k * 64 + n];
    _Float16 hi = (_Float16)v;
    whi[idx] = hi;
    wlo[idx] = (_Float16)(v - (float)hi);
}

// ===== MFMA GEMM: t1[i,:] = fp16( dinv[i] * (X[i,:] @ W1) ), split-fp16 accuracy =====
__global__ __launch_bounds__(256) void gemm_mfma(const float* __restrict__ x,
                                                 const _Float16* __restrict__ whi,
                                                 const _Float16* __restrict__ wlo,
                                                 const float* __restrict__ dinv,
                                                 _Float16* __restrict__ out, int N) {
    int wave = threadIdx.x >> 6;
    int lane = threadIdx.x & 63;
    int base = blockIdx.x * 128 + wave * 32;
    int row = base + (lane & 31);
    int rowc = min(row, N - 1);
    const float* xrow = x + (size_t)rowc * 128 + (lane >> 5) * 8;

    f32x16 acc0, acc1;
#pragma unroll
    for (int i = 0; i < 16; i++) { acc0[i] = 0.f; acc1[i] = 0.f; }

#pragma unroll
    for (int kk = 0; kk < 8; kk++) {
        float4 xa = *reinterpret_cast<const float4*>(xrow + kk * 16);
        float4 xb = *reinterpret_cast<const float4*>(xrow + kk * 16 + 4);
        float xv[8] = {xa.x, xa.y, xa.z, xa.w, xb.x, xb.y, xb.z, xb.w};
        h8 ahi, alo;
#pragma unroll
        for (int j = 0; j < 8; j++) {
            _Float16 hi = (_Float16)xv[j];
            ahi[j] = hi;
            alo[j] = (_Float16)(xv[j] - (float)hi);
        }
        h8 b0h = *reinterpret_cast<const h8*>(whi + (size_t)(kk * 64 + lane) * 8);
        h8 b0l = *reinterpret_cast<const h8*>(wlo + (size_t)(kk * 64 + lane) * 8);
        h8 b1h = *reinterpret_cast<const h8*>(whi + (size_t)((8 + kk) * 64 + lane) * 8);
        h8 b1l = *reinterpret_cast<const h8*>(wlo + (size_t)((8 + kk) * 64 + lane) * 8);
        acc0 = __builtin_amdgcn_mfma_f32_32x32x16_f16(ahi, b0h, acc0, 0, 0, 0);
        acc0 = __builtin_amdgcn_mfma_f32_32x32x16_f16(ahi, b0l, acc0, 0, 0, 0);
        acc0 = __builtin_amdgcn_mfma_f32_32x32x16_f16(alo, b0h, acc0, 0, 0, 0);
        acc1 = __builtin_amdgcn_mfma_f32_32x32x16_f16(ahi, b1h, acc1, 0, 0, 0);
        acc1 = __builtin_amdgcn_mfma_f32_32x32x16_f16(ahi, b1l, acc1, 0, 0, 0);
        acc1 = __builtin_amdgcn_mfma_f32_32x32x16_f16(alo, b1h, acc1, 0, 0, 0);
    }

    // C/D layout: col = lane&31, row = (reg&3) + 8*(reg>>2) + 4*(lane>>5)
    int col = lane & 31;
    int rbase = base + 4 * (lane >> 5);
#pragma unroll
    for (int reg = 0; reg < 16; reg++) {
        int node = rbase + (reg & 3) + 8 * (reg >> 2);
        if (node < N) {
            float di = dinv[node];
            out[(size_t)node * 64 + col] = (_Float16)(di * acc0[reg]);
            out[(size_t)node * 64 + 32 + col] = (_Float16)(di * acc1[reg]);
        }
    }
}

// ===== Layer-1 CSR agg, XCD-split by feature quarter =====
// quarter = blockIdx&3: with round-robin block->XCD dispatch, each XCD touches only a
// 3.2 MB slice of the fp16 table -> L2-resident. Wave: f2 = lane&1 (octet within
// quarter), g32 = lane>>1 (32 edges in flight). Guarded loads skip invalid edge slots.
// Emits qpart[i*4+quarter] = dinv*dot_quarter(relu(dinv*acc + b1), w2l).
#define AGG_NPB 32
__global__ __launch_bounds__(256) void agg1_kernel(const _Float16* __restrict__ t,
                                                   const int2* __restrict__ row2,
                                                   const int* __restrict__ csr,
                                                   const float* __restrict__ dinv,
                                                   const float* __restrict__ b1,
                                                   const float* __restrict__ w2l,
                                                   float* __restrict__ qpart, int N) {
    int quarter = blockIdx.x & 3;
    int chunk = blockIdx.x >> 2;
    int lane = threadIdx.x & 63;
    int w = threadIdx.x >> 6;
    int f2 = lane & 1;
    int g32 = lane >> 1;
    int fb = quarter * 4 + f2 * 2;  // float4 index: features [quarter*16 + f2*8, +8)
    float4 b1v0 = reinterpret_cast<const float4*>(b1)[fb];
    float4 b1v1 = reinterpret_cast<const float4*>(b1)[fb + 1];
    float4 wlv0 = reinterpret_cast<const float4*>(w2l)[fb];
    float4 wlv1 = reinterpret_cast<const float4*>(w2l)[fb + 1];
    const _Float16* tq = t + quarter * 16 + f2 * 8;
    int i0 = chunk * AGG_NPB;
    int iend = min(i0 + AGG_NPB, N);
    for (int i = i0 + w; i < iend; i += 4) {
        int2 rr = row2[i];
        int rs = rr.x, re = rr.y;
        float4 a0 = make_float4(0.f, 0.f, 0.f, 0.f);
        float4 a1 = make_float4(0.f, 0.f, 0.f, 0.f);
        if (g32 == 0) {  // self loop
            h8 sv = *reinterpret_cast<const h8*>(tq + (size_t)i * 64);
            a0.x = (float)sv[0]; a0.y = (float)sv[1]; a0.z = (float)sv[2]; a0.w = (float)sv[3];
            a1.x = (float)sv[4]; a1.y = (float)sv[5]; a1.z = (float)sv[6]; a1.w = (float)sv[7];
        }
        for (int base = rs; base < re; base += 64) {
            int m = re - base;
            int ecl = min(m, 64);
            int idx = csr[base + min(lane, m - 1)];  // splat up to 64 edge ids
            for (int kb = 0; kb < ecl; kb += 32) {
                int epos = kb + g32;
                int s = __shfl(idx, epos, 64);
                if (epos < ecl) {
                    h8 v = *reinterpret_cast<const h8*>(tq + (size_t)s * 64);
                    a0.x += (float)v[0]; a0.y += (float)v[1];
                    a0.z += (float)v[2]; a0.w += (float)v[3];
                    a1.x += (float)v[4]; a1.y += (float)v[5];
                    a1.z += (float)v[6]; a1.w += (float)v[7];
                }
            }
        }
        // reduce over g32 groups (bit0 = f2 preserved under xor 2..32)
#pragma unroll
        for (int off = 2; off <= 32; off <<= 1) {
            a0.x += __shfl_xor(a0.x, off, 64);
            a0.y += __shfl_xor(a0.y, off, 64);
            a0.z += __shfl_xor(a0.z, off, 64);
            a0.w += __shfl_xor(a0.w, off, 64);
            a1.x += __shfl_xor(a1.x, off, 64);
            a1.y += __shfl_xor(a1.y, off, 64);
            a1.z += __shfl_xor(a1.z, off, 64);
            a1.w += __shfl_xor(a1.w, off, 64);
        }
        float di = dinv[i];
        float p = fmaxf(di * a0.x + b1v0.x, 0.f) * wlv0.x
                + fmaxf(di * a0.y + b1v0.y, 0.f) * wlv0.y
                + fmaxf(di * a0.z + b1v0.z, 0.f) * wlv0.z
                + fmaxf(di * a0.w + b1v0.w, 0.f) * wlv0.w
                + fmaxf(di * a1.x + b1v1.x, 0.f) * wlv1.x
                + fmaxf(di * a1.y + b1v1.y, 0.f) * wlv1.y
                + fmaxf(di * a1.z + b1v1.z, 0.f) * wlv1.z
                + fmaxf(di * a1.w + b1v1.w, 0.f) * wlv1.w;
        p += __shfl_xor(p, 1, 64);  // merge f2 halves
        if (lane == 0) qpart[(size_t)i * 4 + quarter] = di * p;
    }
}

__global__ void qcombine_kernel(const float4* __restrict__ qpart, float* __restrict__ q, int N) {
    int i = blockIdx.x * 256 + threadIdx.x;
    if (i < N) {
        float4 v = qpart[i];
        q[i] = v.x + v.y + v.z + v.w;
    }
}

// ================= Layer-2 scalar agg + pooled sum (batch sorted -> LDS bins) =================
__global__ __launch_bounds__(256) void agg2_pool_kernel(const float* __restrict__ q,
                                                        const int2* __restrict__ row2,
                                                        const int* __restrict__ csr,
                                                        const float* __restrict__ dinv,
                                                        const int* __restrict__ batch,
                                                        float* __restrict__ gsum, int N) {
    __shared__ float bins[256];
    bins[threadIdx.x] = 0.0f;
    __syncthreads();
    int i = blockIdx.x * 256 + threadIdx.x;
    if (i < N) {
        int2 rr = row2[i];
        float acc = q[i];  // self loop
        for (int j = rr.x; j < rr.y; j++) acc += q[csr[j]];
        atomicAdd(&bins[batch[i]], dinv[i] * acc);
    }
    __syncthreads();
    int i0 = blockIdx.x * 256;
    if (i0 < N) {
        int ilast = min(i0 + 255, N - 1);
        int gmin = batch[i0];
        int gmax = batch[ilast];
        for (int g = gmin + (int)threadIdx.x; g <= gmax; g += 256)
            atomicAdd(&gsum[g], bins[g]);
    }
}

// ---- out[g] = gsum[g]/cnt[g] + dot(b2,Wl) + bl ; cnt via binary search on sorted batch ----
__global__ void out_kernel(const float* __restrict__ gsum, const int* __restrict__ batch,
                           const float* __restrict__ b2, const float* __restrict__ Wl,
                           const float* __restrict__ bl, float* __restrict__ out, int N) {
    int g = threadIdx.x;
    int lo = 0, hi = N;
    while (lo < hi) { int m = (lo + hi) >> 1; if (batch[m] < g) lo = m + 1; else hi = m; }
    int start = lo;
    hi = N;
    while (lo < hi) { int m = (lo + hi) >> 1; if (batch[m] < g + 1) lo = m + 1; else hi = m; }
    int cnt = lo - start;
    float c = 0.0f;
    for (int f = 0; f < 64; f++) c += b2[f] * Wl[f];
    out[g] = gsum[g] / fmaxf((float)cnt, 1.0f) + c + bl[0];
}

extern "C" void kernel_launch(void* const* d_in, const int* in_sizes, int n_in,
                              void* d_out, int out_size, void* d_ws, size_t ws_size,
                              hipStream_t stream) {
    const float* x  = (const float*)d_in[0];
    const int*   ei = (const int*)d_in[1];
    const int*   batch = (const int*)d_in[2];
    const float* W1 = (const float*)d_in[3];
    const float* b1 = (const float*)d_in[4];
    const float* W2 = (const float*)d_in[5];
    const float* b2 = (const float*)d_in[6];
    const float* Wl = (const float*)d_in[7];
    const float* bl = (const float*)d_in[8];
    float* out = (float*)d_out;

    const int N = N_NODES, E = N_EDGES;
    const int nblk = (N + 255) / 256;  // 391
    const int* src = ei;
    const int* dst = ei + E;

    // workspace layout (bytes; big aligned blocks first)
    char* ws = (char*)d_ws;
    int2*     ebuf      = (int2*)ws;      ws += (size_t)R_BUCKETS * CAP * 8;  // 16.8 MB
    int*      csr       = (int*)ws;       ws += (size_t)R_BUCKETS * CAP * 4;  // 8.4 MB
    _Float16* buf1      = (_Float16*)ws;  ws += 6400000 * 2;                  // t1 (fp16)
    float*    qpart     = (float*)ws;     ws += 100096 * 16;                  // float4/node
    int2*     row2      = (int2*)ws;      ws += 100096 * 8;
    float*    dinv      = (float*)ws;     ws += 100096 * 4;
    float*    q         = (float*)ws;     ws += 100096 * 4;
    float*    gsum      = (float*)ws;     ws += 256 * 4;
    int*      bucket_alloc = (int*)ws;    ws += 256 * 4;
    float*    w2l       = (float*)ws;     ws += 256 * 4;
    _Float16* whi       = (_Float16*)ws;  ws += 8192 * 2;
    _Float16* wlo       = (_Float16*)ws;  ws += 8192 * 2;

    hipMemsetAsync(gsum, 0, 2048, stream);  // gsum + bucket_alloc (adjacent)

    // CSR build: segmented bucket scatter -> per-bucket build (256 blocks, no global scan)
    bkt_scatter<<<NC, 256, 0, stream>>>(src, dst, bucket_alloc, ebuf, E);
    bkt_build<<<R_BUCKETS, 256, 0, stream>>>(ebuf, bucket_alloc, row2, dinv, csr, N);

    w2l_kernel<<<1, 64, 0, stream>>>(W2, Wl, w2l);
    w1split_kernel<<<32, 256, 0, stream>>>(W1, whi, wlo);

    // Layer 1 GEMM on matrix cores: t1 = fp16(dinv*(x@W1))
    gemm_mfma<<<(N + 127) / 128, 256, 0, stream>>>(x, whi, wlo, dinv, buf1, N);

    // Layer-1 aggregation, feature-quartered for XCD L2 locality
    agg1_kernel<<<((N + AGG_NPB - 1) / AGG_NPB) * 4, 256, 0, stream>>>(
        buf1, row2, csr, dinv, b1, w2l, qpart, N);
    qcombine_kernel<<<nblk, 256, 0, stream>>>((const float4*)qpart, q, N);

    // Layer-2 scalar aggregation + mean-pool numerator
    agg2_pool_kernel<<<nblk, 256, 0, stream>>>(q, row2, csr, dinv, batch, gsum, N);

    out_kernel<<<1, 256, 0, stream>>>(gsum, batch, b2, Wl, bl, out, N);
}

// Round 10
// 219.007 us; speedup vs baseline: 1.6290x; 1.6290x over previous
//
#include <hip/hip_runtime.h>

#define N_NODES 100000
#define N_EDGES 1200000
#define R_BUCKETS 256
#define RSZ 400              // 256 * 400 = 102400 >= N
#define CAP 8192             // per-bucket segment capacity (mean 4688 -> safe)
#define CH 4096
#define NC 293               // ceil(1200000 / 4096)

typedef _Float16 h8 __attribute__((ext_vector_type(8)));
typedef float f32x16 __attribute__((ext_vector_type(16)));

// ================= CSR build: segmented buckets, no global scan =================
// S1: per-chunk LDS histogram -> one global atomicAdd per (chunk,bucket) -> LDS-ticket scatter
__global__ __launch_bounds__(256) void bkt_scatter(const int* __restrict__ src,
                                                   const int* __restrict__ dst,
                                                   int* __restrict__ bucket_alloc,
                                                   int2* __restrict__ ebuf, int E) {
    __shared__ int h[R_BUCKETS];
    __shared__ int off[R_BUCKETS];
    h[threadIdx.x] = 0;
    __syncthreads();
    int e0 = blockIdx.x * CH;
    int e1 = min(e0 + CH, E);
    for (int e = e0 + (int)threadIdx.x; e < e1; e += 256)
        atomicAdd(&h[dst[e] / RSZ], 1);
    __syncthreads();
    int b = threadIdx.x;
    int hc = h[b];
    off[b] = b * CAP + (hc > 0 ? atomicAdd(&bucket_alloc[b], hc) : 0);
    __syncthreads();
    for (int e = e0 + (int)threadIdx.x; e < e1; e += 256) {
        int d = dst[e];
        int p = atomicAdd(&off[d / RSZ], 1);
        ebuf[p] = make_int2(src[e], d);
    }
}

// S2: per-bucket (256 blocks): LDS hist -> dinv, LDS scan -> row2, ticket pass -> csr
__global__ __launch_bounds__(256) void bkt_build(const int2* __restrict__ ebuf,
                                                 const int* __restrict__ bcnt,
                                                 int2* __restrict__ row2,
                                                 float* __restrict__ dinv,
                                                 int* __restrict__ csr, int N) {
    __shared__ int hist[RSZ];
    __shared__ int pref[RSZ];
    __shared__ int part[256];
    int r = blockIdx.x;
    int nbase = r * RSZ;
    int ebase = r * CAP;
    int ecnt = bcnt[r];
    for (int i = threadIdx.x; i < RSZ; i += 256) hist[i] = 0;
    __syncthreads();
    for (int e = (int)threadIdx.x; e < ecnt; e += 256)
        atomicAdd(&hist[ebuf[ebase + e].y - nbase], 1);
    __syncthreads();
    for (int i = threadIdx.x; i < RSZ; i += 256) {
        int gi = nbase + i;
        if (gi < N) dinv[gi] = rsqrtf((float)hist[i] + 1.0f);  // +1 self loop
    }
    // exclusive scan of hist (2 bins/thread; RSZ=400 even)
    int s0 = threadIdx.x * 2;
    int sum = (s0 < RSZ) ? hist[s0] + hist[s0 + 1] : 0;
    part[threadIdx.x] = sum;
    __syncthreads();
    for (int off = 1; off < 256; off <<= 1) {
        int v = (threadIdx.x >= off) ? part[threadIdx.x - off] : 0;
        __syncthreads();
        part[threadIdx.x] += v;
        __syncthreads();
    }
    if (s0 < RSZ) {
        int run = part[threadIdx.x] - sum;
        pref[s0] = run;
        pref[s0 + 1] = run + hist[s0];
    }
    __syncthreads();
    for (int i = threadIdx.x; i < RSZ; i += 256) {
        int gi = nbase + i;
        if (gi < N) row2[gi] = make_int2(ebase + pref[i], ebase + pref[i] + hist[i]);
    }
    __syncthreads();
    for (int e = (int)threadIdx.x; e < ecnt; e += 256) {
        int2 sd = ebuf[ebase + e];
        int t = atomicAdd(&pref[sd.y - nbase], 1);
        csr[ebase + t] = sd.x;
    }
}

// ================= w2l = W2 @ Wl =================
__global__ void w2l_kernel(const float* __restrict__ W2, const float* __restrict__ Wl,
                           float* __restrict__ w2l) {
    int f = threadIdx.x;  // 64 threads
    float s = 0.0f;
    for (int o = 0; o < 64; o++) s += W2[f * 64 + o] * Wl[o];
    w2l[f] = s;
}

// ===== W1 -> split-fp16 B-fragments for mfma_f32_32x32x16_f16 =====
__global__ void w1split_kernel(const float* __restrict__ W1, _Float16* __restrict__ whi,
                               _Float16* __restrict__ wlo) {
    int idx = blockIdx.x * 256 + threadIdx.x;  // 2*8*64*8 = 8192
    if (idx >= 8192) return;
    int j = idx & 7;
    int lane = (idx >> 3) & 63;
    int kk = (idx >> 9) & 7;
    int nt = idx >> 12;
    int k = kk * 16 + (lane >> 5) * 8 + j;
    int n = nt * 32 + (lane & 31);
    float v = W1[k * 64 + n];
    _Float16 hi = (_Float16)v;
    whi[idx] = hi;
    wlo[idx] = (_Float16)(v - (float)hi);
}

// ===== MFMA GEMM: t1[i,:] = fp16( dinv[i] * (X[i,:] @ W1) ), split-fp16 accuracy =====
__global__ __launch_bounds__(256) void gemm_mfma(const float* __restrict__ x,
                                                 const _Float16* __restrict__ whi,
                                                 const _Float16* __restrict__ wlo,
                                                 const float* __restrict__ dinv,
                                                 _Float16* __restrict__ out, int N) {
    int wave = threadIdx.x >> 6;
    int lane = threadIdx.x & 63;
    int base = blockIdx.x * 128 + wave * 32;
    int row = base + (lane & 31);
    int rowc = min(row, N - 1);
    const float* xrow = x + (size_t)rowc * 128 + (lane >> 5) * 8;

    f32x16 acc0, acc1;
#pragma unroll
    for (int i = 0; i < 16; i++) { acc0[i] = 0.f; acc1[i] = 0.f; }

#pragma unroll
    for (int kk = 0; kk < 8; kk++) {
        float4 xa = *reinterpret_cast<const float4*>(xrow + kk * 16);
        float4 xb = *reinterpret_cast<const float4*>(xrow + kk * 16 + 4);
        float xv[8] = {xa.x, xa.y, xa.z, xa.w, xb.x, xb.y, xb.z, xb.w};
        h8 ahi, alo;
#pragma unroll
        for (int j = 0; j < 8; j++) {
            _Float16 hi = (_Float16)xv[j];
            ahi[j] = hi;
            alo[j] = (_Float16)(xv[j] - (float)hi);
        }
        h8 b0h = *reinterpret_cast<const h8*>(whi + (size_t)(kk * 64 + lane) * 8);
        h8 b0l = *reinterpret_cast<const h8*>(wlo + (size_t)(kk * 64 + lane) * 8);
        h8 b1h = *reinterpret_cast<const h8*>(whi + (size_t)((8 + kk) * 64 + lane) * 8);
        h8 b1l = *reinterpret_cast<const h8*>(wlo + (size_t)((8 + kk) * 64 + lane) * 8);
        acc0 = __builtin_amdgcn_mfma_f32_32x32x16_f16(ahi, b0h, acc0, 0, 0, 0);
        acc0 = __builtin_amdgcn_mfma_f32_32x32x16_f16(ahi, b0l, acc0, 0, 0, 0);
        acc0 = __builtin_amdgcn_mfma_f32_32x32x16_f16(alo, b0h, acc0, 0, 0, 0);
        acc1 = __builtin_amdgcn_mfma_f32_32x32x16_f16(ahi, b1h, acc1, 0, 0, 0);
        acc1 = __builtin_amdgcn_mfma_f32_32x32x16_f16(ahi, b1l, acc1, 0, 0, 0);
        acc1 = __builtin_amdgcn_mfma_f32_32x32x16_f16(alo, b1h, acc1, 0, 0, 0);
    }

    // C/D layout: col = lane&31, row = (reg&3) + 8*(reg>>2) + 4*(lane>>5)
    int col = lane & 31;
    int rbase = base + 4 * (lane >> 5);
#pragma unroll
    for (int reg = 0; reg < 16; reg++) {
        int node = rbase + (reg & 3) + 8 * (reg >> 2);
        if (node < N) {
            float di = dinv[node];
            out[(size_t)node * 64 + col] = (_Float16)(di * acc0[reg]);
            out[(size_t)node * 64 + 32 + col] = (_Float16)(di * acc1[reg]);
        }
    }
}

// ===== Layer-1 CSR agg over fp16 rows (128 B), wave/node, 8 edges in flight =====
// (R8 form — whole-row gather; feature-splitting below line size was a 2x fetch regression)
#define AGG_NPB 32
__global__ __launch_bounds__(256) void agg1_kernel(const _Float16* __restrict__ t,
                                                   const int2* __restrict__ row2,
                                                   const int* __restrict__ csr,
                                                   const float* __restrict__ dinv,
                                                   const float* __restrict__ b1,
                                                   const float* __restrict__ w2l,
                                                   float* __restrict__ q, int N) {
    int lane = threadIdx.x & 63;
    int w = threadIdx.x >> 6;
    int g8 = lane >> 3;
    int f8 = lane & 7;
    float4 b1a = reinterpret_cast<const float4*>(b1)[f8 * 2];
    float4 b1b = reinterpret_cast<const float4*>(b1)[f8 * 2 + 1];
    float4 wla = reinterpret_cast<const float4*>(w2l)[f8 * 2];
    float4 wlb = reinterpret_cast<const float4*>(w2l)[f8 * 2 + 1];
    int i0 = blockIdx.x * AGG_NPB;
    int iend = min(i0 + AGG_NPB, N);
    for (int i = i0 + w; i < iend; i += 4) {
        int2 rr = row2[i];
        int rs = rr.x, re = rr.y;
        float4 a0 = make_float4(0.f, 0.f, 0.f, 0.f);
        float4 a1 = make_float4(0.f, 0.f, 0.f, 0.f);
        if (g8 == 0) {  // self loop
            h8 sv = *reinterpret_cast<const h8*>(t + (size_t)i * 64 + f8 * 8);
            a0.x = (float)sv[0]; a0.y = (float)sv[1]; a0.z = (float)sv[2]; a0.w = (float)sv[3];
            a1.x = (float)sv[4]; a1.y = (float)sv[5]; a1.z = (float)sv[6]; a1.w = (float)sv[7];
        }
        for (int base = rs; base < re; base += 64) {
            int m = re - base;
            int ecl = min(m, 64);
            int idx = csr[base + min(lane, m - 1)];  // splat up to 64 edge ids
            for (int kb = 0; kb < ecl; kb += 8) {
                int s = __shfl(idx, kb + g8, 64);
                h8 v = *reinterpret_cast<const h8*>(t + (size_t)s * 64 + f8 * 8);
                if (kb + g8 < ecl) {
                    a0.x += (float)v[0]; a0.y += (float)v[1];
                    a0.z += (float)v[2]; a0.w += (float)v[3];
                    a1.x += (float)v[4]; a1.y += (float)v[5];
                    a1.z += (float)v[6]; a1.w += (float)v[7];
                }
            }
        }
#pragma unroll
        for (int off = 8; off <= 32; off <<= 1) {
            a0.x += __shfl_xor(a0.x, off, 64);
            a0.y += __shfl_xor(a0.y, off, 64);
            a0.z += __shfl_xor(a0.z, off, 64);
            a0.w += __shfl_xor(a0.w, off, 64);
            a1.x += __shfl_xor(a1.x, off, 64);
            a1.y += __shfl_xor(a1.y, off, 64);
            a1.z += __shfl_xor(a1.z, off, 64);
            a1.w += __shfl_xor(a1.w, off, 64);
        }
        float di = dinv[i];
        float p = fmaxf(di * a0.x + b1a.x, 0.f) * wla.x
                + fmaxf(di * a0.y + b1a.y, 0.f) * wla.y
                + fmaxf(di * a0.z + b1a.z, 0.f) * wla.z
                + fmaxf(di * a0.w + b1a.w, 0.f) * wla.w
                + fmaxf(di * a1.x + b1b.x, 0.f) * wlb.x
                + fmaxf(di * a1.y + b1b.y, 0.f) * wlb.y
                + fmaxf(di * a1.z + b1b.z, 0.f) * wlb.z
                + fmaxf(di * a1.w + b1b.w, 0.f) * wlb.w;
        p += __shfl_xor(p, 1, 64);
        p += __shfl_xor(p, 2, 64);
        p += __shfl_xor(p, 4, 64);
        if (lane == 0) q[i] = di * p;
    }
}

// ================= Layer-2 scalar agg + pooled sum (batch sorted -> LDS bins) =================
__global__ __launch_bounds__(256) void agg2_pool_kernel(const float* __restrict__ q,
                                                        const int2* __restrict__ row2,
                                                        const int* __restrict__ csr,
                                                        const float* __restrict__ dinv,
                                                        const int* __restrict__ batch,
                                                        float* __restrict__ gsum, int N) {
    __shared__ float bins[256];
    bins[threadIdx.x] = 0.0f;
    __syncthreads();
    int i = blockIdx.x * 256 + threadIdx.x;
    if (i < N) {
        int2 rr = row2[i];
        float acc = q[i];  // self loop
        for (int j = rr.x; j < rr.y; j++) acc += q[csr[j]];
        atomicAdd(&bins[batch[i]], dinv[i] * acc);
    }
    __syncthreads();
    int i0 = blockIdx.x * 256;
    if (i0 < N) {
        int ilast = min(i0 + 255, N - 1);
        int gmin = batch[i0];
        int gmax = batch[ilast];
        for (int g = gmin + (int)threadIdx.x; g <= gmax; g += 256)
            atomicAdd(&gsum[g], bins[g]);
    }
}

// ---- out[g] = gsum[g]/cnt[g] + dot(b2,Wl) + bl ; cnt via binary search on sorted batch ----
__global__ void out_kernel(const float* __restrict__ gsum, const int* __restrict__ batch,
                           const float* __restrict__ b2, const float* __restrict__ Wl,
                           const float* __restrict__ bl, float* __restrict__ out, int N) {
    int g = threadIdx.x;
    int lo = 0, hi = N;
    while (lo < hi) { int m = (lo + hi) >> 1; if (batch[m] < g) lo = m + 1; else hi = m; }
    int start = lo;
    hi = N;
    while (lo < hi) { int m = (lo + hi) >> 1; if (batch[m] < g + 1) lo = m + 1; else hi = m; }
    int cnt = lo - start;
    float c = 0.0f;
    for (int f = 0; f < 64; f++) c += b2[f] * Wl[f];
    out[g] = gsum[g] / fmaxf((float)cnt, 1.0f) + c + bl[0];
}

extern "C" void kernel_launch(void* const* d_in, const int* in_sizes, int n_in,
                              void* d_out, int out_size, void* d_ws, size_t ws_size,
                              hipStream_t stream) {
    const float* x  = (const float*)d_in[0];
    const int*   ei = (const int*)d_in[1];
    const int*   batch = (const int*)d_in[2];
    const float* W1 = (const float*)d_in[3];
    const float* b1 = (const float*)d_in[4];
    const float* W2 = (const float*)d_in[5];
    const float* b2 = (const float*)d_in[6];
    const float* Wl = (const float*)d_in[7];
    const float* bl = (const float*)d_in[8];
    float* out = (float*)d_out;

    const int N = N_NODES, E = N_EDGES;
    const int nblk = (N + 255) / 256;  // 391
    const int* src = ei;
    const int* dst = ei + E;

    // workspace layout (bytes; big aligned blocks first)
    char* ws = (char*)d_ws;
    int2*     ebuf      = (int2*)ws;      ws += (size_t)R_BUCKETS * CAP * 8;  // 16.8 MB
    int*      csr       = (int*)ws;       ws += (size_t)R_BUCKETS * CAP * 4;  // 8.4 MB
    _Float16* buf1      = (_Float16*)ws;  ws += 6400000 * 2;                  // t1 (fp16)
    int2*     row2      = (int2*)ws;      ws += 100096 * 8;
    float*    dinv      = (float*)ws;     ws += 100096 * 4;
    float*    q         = (float*)ws;     ws += 100096 * 4;
    float*    gsum      = (float*)ws;     ws += 256 * 4;
    int*      bucket_alloc = (int*)ws;    ws += 256 * 4;
    float*    w2l       = (float*)ws;     ws += 256 * 4;
    _Float16* whi       = (_Float16*)ws;  ws += 8192 * 2;
    _Float16* wlo       = (_Float16*)ws;  ws += 8192 * 2;

    hipMemsetAsync(gsum, 0, 2048, stream);  // gsum + bucket_alloc (adjacent)

    // CSR build: segmented bucket scatter -> per-bucket build (256 blocks, no global scan)
    bkt_scatter<<<NC, 256, 0, stream>>>(src, dst, bucket_alloc, ebuf, E);
    bkt_build<<<R_BUCKETS, 256, 0, stream>>>(ebuf, bucket_alloc, row2, dinv, csr, N);

    w2l_kernel<<<1, 64, 0, stream>>>(W2, Wl, w2l);
    w1split_kernel<<<32, 256, 0, stream>>>(W1, whi, wlo);

    // Layer 1 GEMM on matrix cores: t1 = fp16(dinv*(x@W1))
    gemm_mfma<<<(N + 127) / 128, 256, 0, stream>>>(x, whi, wlo, dinv, buf1, N);

    // Layer-1 aggregation fused with folded layer-2 GEMM -> scalar q per node
    agg1_kernel<<<(N + AGG_NPB - 1) / AGG_NPB, 256, 0, stream>>>(
        buf1, row2, csr, dinv, b1, w2l, q, N);

    // Layer-2 scalar aggregation + mean-pool numerator
    agg2_pool_kernel<<<nblk, 256, 0, stream>>>(q, row2, csr, dinv, batch, gsum, N);

    out_kernel<<<1, 256, 0, stream>>>(gsum, batch, b2, Wl, bl, out, N);
}

// Round 11
// 218.770 us; speedup vs baseline: 1.6307x; 1.0011x over previous
//
#include <hip/hip_runtime.h>

#define N_NODES 100000
#define N_EDGES 1200000
#define R_BUCKETS 256
#define RSZ 400              // 256 * 400 = 102400 >= N
#define CAP 8192             // per-bucket segment capacity (mean 4688 -> safe)
#define CH 4096
#define NC 293               // ceil(1200000 / 4096)

typedef _Float16 h8 __attribute__((ext_vector_type(8)));
typedef float f32x16 __attribute__((ext_vector_type(16)));

// ================= CSR build: segmented buckets, packed 32-bit edge records =================
// S1: per-chunk LDS histogram -> one global atomicAdd per (chunk,bucket) -> LDS-ticket scatter
// Edge record: (src << 9) | (dst - bucket*RSZ)   [src < 2^17, local d < 512]
__global__ __launch_bounds__(256) void bkt_scatter(const int* __restrict__ src,
                                                   const int* __restrict__ dst,
                                                   int* __restrict__ bucket_alloc,
                                                   int* __restrict__ ebuf, int E) {
    __shared__ int h[R_BUCKETS];
    __shared__ int off[R_BUCKETS];
    h[threadIdx.x] = 0;
    __syncthreads();
    int e0 = blockIdx.x * CH;
    int e1 = min(e0 + CH, E);
    for (int e = e0 + (int)threadIdx.x; e < e1; e += 256)
        atomicAdd(&h[dst[e] / RSZ], 1);
    __syncthreads();
    int b = threadIdx.x;
    int hc = h[b];
    off[b] = b * CAP + (hc > 0 ? atomicAdd(&bucket_alloc[b], hc) : 0);
    __syncthreads();
    for (int e = e0 + (int)threadIdx.x; e < e1; e += 256) {
        int d = dst[e];
        int bk = d / RSZ;
        int p = atomicAdd(&off[bk], 1);
        ebuf[p] = (src[e] << 9) | (d - bk * RSZ);
    }
}

// S2: per-bucket (256 blocks): LDS hist -> dinv, LDS scan -> row2, ticket pass -> csr
__global__ __launch_bounds__(256) void bkt_build(const int* __restrict__ ebuf,
                                                 const int* __restrict__ bcnt,
                                                 int2* __restrict__ row2,
                                                 float* __restrict__ dinv,
                                                 int* __restrict__ csr, int N) {
    __shared__ int hist[RSZ];
    __shared__ int pref[RSZ];
    __shared__ int part[256];
    int r = blockIdx.x;
    int nbase = r * RSZ;
    int ebase = r * CAP;
    int ecnt = bcnt[r];
    for (int i = threadIdx.x; i < RSZ; i += 256) hist[i] = 0;
    __syncthreads();
    for (int e = (int)threadIdx.x; e < ecnt; e += 256)
        atomicAdd(&hist[ebuf[ebase + e] & 511], 1);
    __syncthreads();
    for (int i = threadIdx.x; i < RSZ; i += 256) {
        int gi = nbase + i;
        if (gi < N) dinv[gi] = rsqrtf((float)hist[i] + 1.0f);  // +1 self loop
    }
    // exclusive scan of hist (2 bins/thread; RSZ=400 even)
    int s0 = threadIdx.x * 2;
    int sum = (s0 < RSZ) ? hist[s0] + hist[s0 + 1] : 0;
    part[threadIdx.x] = sum;
    __syncthreads();
    for (int off = 1; off < 256; off <<= 1) {
        int v = (threadIdx.x >= off) ? part[threadIdx.x - off] : 0;
        __syncthreads();
        part[threadIdx.x] += v;
        __syncthreads();
    }
    if (s0 < RSZ) {
        int run = part[threadIdx.x] - sum;
        pref[s0] = run;
        pref[s0 + 1] = run + hist[s0];
    }
    __syncthreads();
    for (int i = threadIdx.x; i < RSZ; i += 256) {
        int gi = nbase + i;
        if (gi < N) row2[gi] = make_int2(ebase + pref[i], ebase + pref[i] + hist[i]);
    }
    __syncthreads();
    for (int e = (int)threadIdx.x; e < ecnt; e += 256) {
        int epk = ebuf[ebase + e];
        int t = atomicAdd(&pref[epk & 511], 1);
        csr[ebase + t] = (int)(((unsigned)epk) >> 9);
    }
}

// ============ prep: w2l = W2@Wl (block 32) + W1 split-fp16 B-fragments (blocks 0..31) ============
__global__ void prep_kernel(const float* __restrict__ W1, const float* __restrict__ W2,
                            const float* __restrict__ Wl, float* __restrict__ w2l,
                            _Float16* __restrict__ whi, _Float16* __restrict__ wlo) {
    if (blockIdx.x == 32) {
        if (threadIdx.x < 64) {
            int f = threadIdx.x;
            float s = 0.0f;
            for (int o = 0; o < 64; o++) s += W2[f * 64 + o] * Wl[o];
            w2l[f] = s;
        }
        return;
    }
    int idx = blockIdx.x * 256 + threadIdx.x;  // 2*8*64*8 = 8192
    int j = idx & 7;
    int lane = (idx >> 3) & 63;
    int kk = (idx >> 9) & 7;
    int nt = idx >> 12;
    int k = kk * 16 + (lane >> 5) * 8 + j;
    int n = nt * 32 + (lane & 31);
    float v = W1[k * 64 + n];
    _Float16 hi = (_Float16)v;
    whi[idx] = hi;
    wlo[idx] = (_Float16)(v - (float)hi);
}

// ===== MFMA GEMM: t1[i,:] = fp16( dinv[i] * (X[i,:] @ W1) ), split-fp16 accuracy =====
__global__ __launch_bounds__(256) void gemm_mfma(const float* __restrict__ x,
                                                 const _Float16* __restrict__ whi,
                                                 const _Float16* __restrict__ wlo,
                                                 const float* __restrict__ dinv,
                                                 _Float16* __restrict__ out, int N) {
    int wave = threadIdx.x >> 6;
    int lane = threadIdx.x & 63;
    int base = blockIdx.x * 128 + wave * 32;
    int row = base + (lane & 31);
    int rowc = min(row, N - 1);
    const float* xrow = x + (size_t)rowc * 128 + (lane >> 5) * 8;

    f32x16 acc0, acc1;
#pragma unroll
    for (int i = 0; i < 16; i++) { acc0[i] = 0.f; acc1[i] = 0.f; }

#pragma unroll
    for (int kk = 0; kk < 8; kk++) {
        float4 xa = *reinterpret_cast<const float4*>(xrow + kk * 16);
        float4 xb = *reinterpret_cast<const float4*>(xrow + kk * 16 + 4);
        float xv[8] = {xa.x, xa.y, xa.z, xa.w, xb.x, xb.y, xb.z, xb.w};
        h8 ahi, alo;
#pragma unroll
        for (int j = 0; j < 8; j++) {
            _Float16 hi = (_Float16)xv[j];
            ahi[j] = hi;
            alo[j] = (_Float16)(xv[j] - (float)hi);
        }
        h8 b0h = *reinterpret_cast<const h8*>(whi + (size_t)(kk * 64 + lane) * 8);
        h8 b0l = *reinterpret_cast<const h8*>(wlo + (size_t)(kk * 64 + lane) * 8);
        h8 b1h = *reinterpret_cast<const h8*>(whi + (size_t)((8 + kk) * 64 + lane) * 8);
        h8 b1l = *reinterpret_cast<const h8*>(wlo + (size_t)((8 + kk) * 64 + lane) * 8);
        acc0 = __builtin_amdgcn_mfma_f32_32x32x16_f16(ahi, b0h, acc0, 0, 0, 0);
        acc0 = __builtin_amdgcn_mfma_f32_32x32x16_f16(ahi, b0l, acc0, 0, 0, 0);
        acc0 = __builtin_amdgcn_mfma_f32_32x32x16_f16(alo, b0h, acc0, 0, 0, 0);
        acc1 = __builtin_amdgcn_mfma_f32_32x32x16_f16(ahi, b1h, acc1, 0, 0, 0);
        acc1 = __builtin_amdgcn_mfma_f32_32x32x16_f16(ahi, b1l, acc1, 0, 0, 0);
        acc1 = __builtin_amdgcn_mfma_f32_32x32x16_f16(alo, b1h, acc1, 0, 0, 0);
    }

    // C/D layout: col = lane&31, row = (reg&3) + 8*(reg>>2) + 4*(lane>>5)
    int col = lane & 31;
    int rbase = base + 4 * (lane >> 5);
#pragma unroll
    for (int reg = 0; reg < 16; reg++) {
        int node = rbase + (reg & 3) + 8 * (reg >> 2);
        if (node < N) {
            float di = dinv[node];
            out[(size_t)node * 64 + col] = (_Float16)(di * acc0[reg]);
            out[(size_t)node * 64 + 32 + col] = (_Float16)(di * acc1[reg]);
        }
    }
}

// ===== Layer-1 CSR agg over fp16 rows (128 B), wave/node, 8 edges in flight =====
// Gather load is PREDICATED: exec-masked lanes fetch nothing, cutting the
// roundup(deg,8) byte waste (~33% at mean degree 12) while loads stay independent.
#define AGG_NPB 32
__global__ __launch_bounds__(256) void agg1_kernel(const _Float16* __restrict__ t,
                                                   const int2* __restrict__ row2,
                                                   const int* __restrict__ csr,
                                                   const float* __restrict__ dinv,
                                                   const float* __restrict__ b1,
                                                   const float* __restrict__ w2l,
                                                   float* __restrict__ q, int N) {
    int lane = threadIdx.x & 63;
    int w = threadIdx.x >> 6;
    int g8 = lane >> 3;
    int f8 = lane & 7;
    float4 b1a = reinterpret_cast<const float4*>(b1)[f8 * 2];
    float4 b1b = reinterpret_cast<const float4*>(b1)[f8 * 2 + 1];
    float4 wla = reinterpret_cast<const float4*>(w2l)[f8 * 2];
    float4 wlb = reinterpret_cast<const float4*>(w2l)[f8 * 2 + 1];
    int i0 = blockIdx.x * AGG_NPB;
    int iend = min(i0 + AGG_NPB, N);
    for (int i = i0 + w; i < iend; i += 4) {
        int2 rr = row2[i];
        int rs = rr.x, re = rr.y;
        float4 a0 = make_float4(0.f, 0.f, 0.f, 0.f);
        float4 a1 = make_float4(0.f, 0.f, 0.f, 0.f);
        if (g8 == 0) {  // self loop
            h8 sv = *reinterpret_cast<const h8*>(t + (size_t)i * 64 + f8 * 8);
            a0.x = (float)sv[0]; a0.y = (float)sv[1]; a0.z = (float)sv[2]; a0.w = (float)sv[3];
            a1.x = (float)sv[4]; a1.y = (float)sv[5]; a1.z = (float)sv[6]; a1.w = (float)sv[7];
        }
        for (int base = rs; base < re; base += 64) {
            int m = re - base;
            int ecl = min(m, 64);
            int idx = csr[base + min(lane, m - 1)];  // splat up to 64 edge ids
            for (int kb = 0; kb < ecl; kb += 8) {
                int s = __shfl(idx, kb + g8, 64);
                if (kb + g8 < ecl) {
                    h8 v = *reinterpret_cast<const h8*>(t + (size_t)s * 64 + f8 * 8);
                    a0.x += (float)v[0]; a0.y += (float)v[1];
                    a0.z += (float)v[2]; a0.w += (float)v[3];
                    a1.x += (float)v[4]; a1.y += (float)v[5];
                    a1.z += (float)v[6]; a1.w += (float)v[7];
                }
            }
        }
#pragma unroll
        for (int off = 8; off <= 32; off <<= 1) {
            a0.x += __shfl_xor(a0.x, off, 64);
            a0.y += __shfl_xor(a0.y, off, 64);
            a0.z += __shfl_xor(a0.z, off, 64);
            a0.w += __shfl_xor(a0.w, off, 64);
            a1.x += __shfl_xor(a1.x, off, 64);
            a1.y += __shfl_xor(a1.y, off, 64);
            a1.z += __shfl_xor(a1.z, off, 64);
            a1.w += __shfl_xor(a1.w, off, 64);
        }
        float di = dinv[i];
        float p = fmaxf(di * a0.x + b1a.x, 0.f) * wla.x
                + fmaxf(di * a0.y + b1a.y, 0.f) * wla.y
                + fmaxf(di * a0.z + b1a.z, 0.f) * wla.z
                + fmaxf(di * a0.w + b1a.w, 0.f) * wla.w
                + fmaxf(di * a1.x + b1b.x, 0.f) * wlb.x
                + fmaxf(di * a1.y + b1b.y, 0.f) * wlb.y
                + fmaxf(di * a1.z + b1b.z, 0.f) * wlb.z
                + fmaxf(di * a1.w + b1b.w, 0.f) * wlb.w;
        p += __shfl_xor(p, 1, 64);
        p += __shfl_xor(p, 2, 64);
        p += __shfl_xor(p, 4, 64);
        if (lane == 0) q[i] = di * p;
    }
}

// ================= Layer-2 scalar agg + pooled sum (batch sorted -> LDS bins) =================
__global__ __launch_bounds__(256) void agg2_pool_kernel(const float* __restrict__ q,
                                                        const int2* __restrict__ row2,
                                                        const int* __restrict__ csr,
                                                        const float* __restrict__ dinv,
                                                        const int* __restrict__ batch,
                                                        float* __restrict__ gsum, int N) {
    __shared__ float bins[256];
    bins[threadIdx.x] = 0.0f;
    __syncthreads();
    int i = blockIdx.x * 256 + threadIdx.x;
    if (i < N) {
        int2 rr = row2[i];
        float acc = q[i];  // self loop
        for (int j = rr.x; j < rr.y; j++) acc += q[csr[j]];
        atomicAdd(&bins[batch[i]], dinv[i] * acc);
    }
    __syncthreads();
    int i0 = blockIdx.x * 256;
    if (i0 < N) {
        int ilast = min(i0 + 255, N - 1);
        int gmin = batch[i0];
        int gmax = batch[ilast];
        for (int g = gmin + (int)threadIdx.x; g <= gmax; g += 256)
            atomicAdd(&gsum[g], bins[g]);
    }
}

// ---- out[g] = gsum[g]/cnt[g] + dot(b2,Wl) + bl ; cnt via binary search on sorted batch ----
__global__ void out_kernel(const float* __restrict__ gsum, const int* __restrict__ batch,
                           const float* __restrict__ b2, const float* __restrict__ Wl,
                           const float* __restrict__ bl, float* __restrict__ out, int N) {
    int g = threadIdx.x;
    int lo = 0, hi = N;
    while (lo < hi) { int m = (lo + hi) >> 1; if (batch[m] < g) lo = m + 1; else hi = m; }
    int start = lo;
    hi = N;
    while (lo < hi) { int m = (lo + hi) >> 1; if (batch[m] < g + 1) lo = m + 1; else hi = m; }
    int cnt = lo - start;
    float c = 0.0f;
    for (int f = 0; f < 64; f++) c += b2[f] * Wl[f];
    out[g] = gsum[g] / fmaxf((float)cnt, 1.0f) + c + bl[0];
}

extern "C" void kernel_launch(void* const* d_in, const int* in_sizes, int n_in,
                              void* d_out, int out_size, void* d_ws, size_t ws_size,
                              hipStream_t stream) {
    const float* x  = (const float*)d_in[0];
    const int*   ei = (const int*)d_in[1];
    const int*   batch = (const int*)d_in[2];
    const float* W1 = (const float*)d_in[3];
    const float* b1 = (const float*)d_in[4];
    const float* W2 = (const float*)d_in[5];
    const float* b2 = (const float*)d_in[6];
    const float* Wl = (const float*)d_in[7];
    const float* bl = (const float*)d_in[8];
    float* out = (float*)d_out;

    const int N = N_NODES, E = N_EDGES;
    const int nblk = (N + 255) / 256;  // 391
    const int* src = ei;
    const int* dst = ei + E;

    // workspace layout (bytes; big aligned blocks first)
    char* ws = (char*)d_ws;
    int*      ebuf      = (int*)ws;       ws += (size_t)R_BUCKETS * CAP * 4;  // 8.4 MB (packed)
    int*      csr       = (int*)ws;       ws += (size_t)R_BUCKETS * CAP * 4;  // 8.4 MB
    _Float16* buf1      = (_Float16*)ws;  ws += 6400000 * 2;                  // t1 (fp16)
    int2*     row2      = (int2*)ws;      ws += 100096 * 8;
    float*    dinv      = (float*)ws;     ws += 100096 * 4;
    float*    q         = (float*)ws;     ws += 100096 * 4;
    float*    gsum      = (float*)ws;     ws += 256 * 4;
    int*      bucket_alloc = (int*)ws;    ws += 256 * 4;
    float*    w2l       = (float*)ws;     ws += 256 * 4;
    _Float16* whi       = (_Float16*)ws;  ws += 8192 * 2;
    _Float16* wlo       = (_Float16*)ws;  ws += 8192 * 2;

    hipMemsetAsync(gsum, 0, 2048, stream);  // gsum + bucket_alloc (adjacent)

    // CSR build: segmented bucket scatter -> per-bucket build (256 blocks, no global scan)
    bkt_scatter<<<NC, 256, 0, stream>>>(src, dst, bucket_alloc, ebuf, E);
    bkt_build<<<R_BUCKETS, 256, 0, stream>>>(ebuf, bucket_alloc, row2, dinv, csr, N);

    prep_kernel<<<33, 256, 0, stream>>>(W1, W2, Wl, w2l, whi, wlo);

    // Layer 1 GEMM on matrix cores: t1 = fp16(dinv*(x@W1))
    gemm_mfma<<<(N + 127) / 128, 256, 0, stream>>>(x, whi, wlo, dinv, buf1, N);

    // Layer-1 aggregation fused with folded layer-2 GEMM -> scalar q per node
    agg1_kernel<<<(N + AGG_NPB - 1) / AGG_NPB, 256, 0, stream>>>(
        buf1, row2, csr, dinv, b1, w2l, q, N);

    // Layer-2 scalar aggregation + mean-pool numerator
    agg2_pool_kernel<<<nblk, 256, 0, stream>>>(q, row2, csr, dinv, batch, gsum, N);

    out_kernel<<<1, 256, 0, stream>>>(gsum, batch, b2, Wl, bl, out, N);
}